// Round 1
// baseline (522.053 us; speedup 1.0000x reference)
//
#include <hip/hip_runtime.h>
#include <math.h>

#define BATCH 8
#define SEQ   2048
#define DIM   1024
#define HD    64

// ---------------------------------------------------------------------------
// Kernel 1: QKV projection.  out = x @ W + b for W in {Wq, Wk, Wv}.
// grid = (B*S/64, 3); block = 256.  Each block computes a 64x64 tile
// (64 rows of x, all 64 head dims) with a 4x4 micro-tile per thread.
// mat 0 -> q [B,S,H], mat 1 -> k stored TRANSPOSED [B,H,S], mat 2 -> v [B,S,H].
// ---------------------------------------------------------------------------
__global__ __launch_bounds__(256)
void qkv_proj_kernel(const float* __restrict__ x,
                     const float* __restrict__ Wq, const float* __restrict__ bq,
                     const float* __restrict__ Wk, const float* __restrict__ bk,
                     const float* __restrict__ Wv, const float* __restrict__ bv,
                     float* __restrict__ q_out,
                     float* __restrict__ kt_out,
                     float* __restrict__ v_out)
{
    const int mat = blockIdx.y;
    const float* __restrict__ W    = (mat == 0) ? Wq : (mat == 1) ? Wk : Wv;
    const float* __restrict__ bias = (mat == 0) ? bq : (mat == 1) ? bk : bv;

    const int row0 = blockIdx.x * 64;
    const int t  = threadIdx.x;
    const int tx = t & 15;        // output col group (4 cols)
    const int ty = t >> 4;        // output row group (4 rows)

    __shared__ float As[64][33];  // [m][k], +1 pad breaks write conflicts
    __shared__ float Bs[32][64];  // [k][n]

    float acc[4][4] = {};

    for (int k0 = 0; k0 < DIM; k0 += 32) {
        // A tile: 64 rows x 32 k.  Coalesced along k.
        {
            const int col   = t & 31;
            const int rbase = t >> 5;
            #pragma unroll
            for (int i = 0; i < 8; ++i) {
                const int m = rbase + i * 8;
                As[m][col] = x[(size_t)(row0 + m) * DIM + k0 + col];
            }
        }
        // B tile: 32 k x 64 n.  Coalesced along n.
        {
            const int col   = t & 63;
            const int rbase = t >> 6;
            #pragma unroll
            for (int i = 0; i < 8; ++i) {
                const int kk = rbase + i * 4;
                Bs[kk][col] = W[(size_t)(k0 + kk) * HD + col];
            }
        }
        __syncthreads();
        #pragma unroll
        for (int kk = 0; kk < 32; ++kk) {
            const float a0 = As[ty * 4 + 0][kk];
            const float a1 = As[ty * 4 + 1][kk];
            const float a2 = As[ty * 4 + 2][kk];
            const float a3 = As[ty * 4 + 3][kk];
            const float4 bv4 = *(const float4*)&Bs[kk][tx * 4];
            acc[0][0] += a0 * bv4.x; acc[0][1] += a0 * bv4.y; acc[0][2] += a0 * bv4.z; acc[0][3] += a0 * bv4.w;
            acc[1][0] += a1 * bv4.x; acc[1][1] += a1 * bv4.y; acc[1][2] += a1 * bv4.z; acc[1][3] += a1 * bv4.w;
            acc[2][0] += a2 * bv4.x; acc[2][1] += a2 * bv4.y; acc[2][2] += a2 * bv4.z; acc[2][3] += a2 * bv4.w;
            acc[3][0] += a3 * bv4.x; acc[3][1] += a3 * bv4.y; acc[3][2] += a3 * bv4.z; acc[3][3] += a3 * bv4.w;
        }
        __syncthreads();
    }

    // bias
    const float4 bb = *(const float4*)&bias[tx * 4];
    #pragma unroll
    for (int i = 0; i < 4; ++i) {
        acc[i][0] += bb.x; acc[i][1] += bb.y; acc[i][2] += bb.z; acc[i][3] += bb.w;
    }

    const int b  = row0 / SEQ;
    const int s0 = (row0 % SEQ) + ty * 4;

    if (mat == 1) {
        // k transposed: kt[b][h][s]
        #pragma unroll
        for (int j = 0; j < 4; ++j) {
            const int h = tx * 4 + j;
            float* p = kt_out + ((size_t)b * HD + h) * SEQ + s0;
            p[0] = acc[0][j]; p[1] = acc[1][j]; p[2] = acc[2][j]; p[3] = acc[3][j];
        }
    } else {
        float* __restrict__ o = (mat == 0) ? q_out : v_out;
        #pragma unroll
        for (int i = 0; i < 4; ++i) {
            float4 vv;
            vv.x = acc[i][0]; vv.y = acc[i][1]; vv.z = acc[i][2]; vv.w = acc[i][3];
            *(float4*)&o[((size_t)b * SEQ + s0 + i) * HD + tx * 4] = vv;
        }
    }
}

// ---------------------------------------------------------------------------
// Kernel 2: flash-style causal attention.
// grid = B*S/8; block = 256 (4 waves).  Each wave owns 2 consecutive q rows;
// lane l owns output dim l.  K/V tiles of 64 rows staged in LDS; online
// softmax (running max m, denom l) per q row with wave shuffle reductions.
// ---------------------------------------------------------------------------
__global__ __launch_bounds__(256)
void attn_kernel(const float* __restrict__ qg,
                 const float* __restrict__ ktg,   // [B][H][S]
                 const float* __restrict__ vg,    // [B][S][H]
                 float* __restrict__ out)         // [B][S][H]
{
    __shared__ float Kt[64][64];   // [d][j]  (j local to tile)
    __shared__ float Vt[64][64];   // [j][d]
    __shared__ float qs[8][64];
    __shared__ float ps[8][64];

    const int bi = blockIdx.x;
    const int b  = bi >> 8;              // 256 blocks per batch
    const int r0 = (bi & 255) * 8;
    const int t  = threadIdx.x;
    const int w  = t >> 6;
    const int l  = t & 63;

    // stage the block's 8 q rows
    #pragma unroll
    for (int i = 0; i < 2; ++i) {
        const int idx = t + i * 256;
        const int r = idx >> 6, d = idx & 63;
        qs[r][d] = qg[((size_t)b * SEQ + r0 + r) * HD + d];
    }

    const int iq[2] = { r0 + 2 * w, r0 + 2 * w + 1 };
    float oacc[2] = {0.f, 0.f};
    float mm[2]   = {-INFINITY, -INFINITY};
    float ll[2]   = {0.f, 0.f};

    const int ntiles = (r0 + 8 + 63) >> 6;
    for (int t0 = 0; t0 < ntiles; ++t0) {
        const int j0 = t0 << 6;
        __syncthreads();   // protect previous tile reads (also covers qs on iter 0)
        // K^T tile: Kt[d][j] <- ktg[b][d][j0+j], coalesced float4 along j
        #pragma unroll
        for (int i = 0; i < 4; ++i) {
            const int d = (t >> 4) + i * 16;
            const int j = (t & 15) * 4;
            *(float4*)&Kt[d][j] = *(const float4*)&ktg[((size_t)b * HD + d) * SEQ + j0 + j];
        }
        // V tile: Vt[j][d] <- vg[b][j0+j][d], fully contiguous
        #pragma unroll
        for (int i = 0; i < 4; ++i) {
            const int j = (t >> 4) + i * 16;
            const int d = (t & 15) * 4;
            *(float4*)&Vt[j][d] = *(const float4*)&vg[((size_t)b * SEQ + j0 + j) * HD + d];
        }
        __syncthreads();

        #pragma unroll
        for (int rr = 0; rr < 2; ++rr) {
            const int i_q = iq[rr];
            if (j0 > i_q) continue;           // wave-uniform: fully-masked tile
            const int rloc = 2 * w + rr;

            // score for k row j = j0 + l
            float s = 0.f;
            #pragma unroll
            for (int d = 0; d < 64; d += 4) {
                const float4 qv = *(const float4*)&qs[rloc][d];  // broadcast
                s += qv.x * Kt[d + 0][l] + qv.y * Kt[d + 1][l]
                   + qv.z * Kt[d + 2][l] + qv.w * Kt[d + 3][l];
            }
            const int j = j0 + l;
            s = (j <= i_q) ? s * 0.125f : -INFINITY;   // mask then scale (== ref)

            // online softmax update
            float tmax = s;
            #pragma unroll
            for (int off = 32; off; off >>= 1)
                tmax = fmaxf(tmax, __shfl_xor(tmax, off, 64));
            const float mnew  = fmaxf(mm[rr], tmax);
            const float alpha = __expf(mm[rr] - mnew);   // exp(-inf)=0 on first tile
            const float p     = __expf(s - mnew);        // masked lanes -> 0
            float psum = p;
            #pragma unroll
            for (int off = 32; off; off >>= 1)
                psum += __shfl_xor(psum, off, 64);
            ll[rr] = ll[rr] * alpha + psum;
            mm[rr] = mnew;

            ps[rloc][l] = p;   // same-wave LDS, in-order: no barrier needed

            float acc = oacc[rr] * alpha;
            #pragma unroll
            for (int jj = 0; jj < 64; ++jj)
                acc += ps[rloc][jj] * Vt[jj][l];   // ps broadcast, Vt 2-way (free)
            oacc[rr] = acc;
        }
    }

    out[((size_t)b * SEQ + iq[0]) * HD + l] = oacc[0] / ll[0];
    out[((size_t)b * SEQ + iq[1]) * HD + l] = oacc[1] / ll[1];
}

// ---------------------------------------------------------------------------
extern "C" void kernel_launch(void* const* d_in, const int* in_sizes, int n_in,
                              void* d_out, int out_size, void* d_ws, size_t ws_size,
                              hipStream_t stream) {
    const float* x  = (const float*)d_in[0];
    const float* Wq = (const float*)d_in[1];
    const float* bq = (const float*)d_in[2];
    const float* Wk = (const float*)d_in[3];
    const float* bk = (const float*)d_in[4];
    const float* Wv = (const float*)d_in[5];
    const float* bv = (const float*)d_in[6];
    float* out = (float*)d_out;

    float* q_ws  = (float*)d_ws;                          // [B,S,H]
    float* kt_ws = q_ws  + (size_t)BATCH * SEQ * HD;      // [B,H,S]
    float* v_ws  = kt_ws + (size_t)BATCH * HD * SEQ;      // [B,S,H]

    qkv_proj_kernel<<<dim3(BATCH * SEQ / 64, 3), 256, 0, stream>>>(
        x, Wq, bq, Wk, bk, Wv, bv, q_ws, kt_ws, v_ws);
    attn_kernel<<<dim3(BATCH * SEQ / 8), 256, 0, stream>>>(q_ws, kt_ws, v_ws, out);
}

// Round 2
// 245.990 us; speedup vs baseline: 2.1223x; 2.1223x over previous
//
#include <hip/hip_runtime.h>
#include <math.h>

#define BATCH 8
#define SEQ   2048
#define DIM   1024
#define HD    64
#define NROWS (BATCH * SEQ)   // 16384

typedef __attribute__((ext_vector_type(8))) short bf16x8;  // 8 bf16 = 4 VGPRs
typedef __attribute__((ext_vector_type(4))) float f32x4;

__device__ __forceinline__ unsigned short f2bf(float f) {
    unsigned u = __float_as_uint(f);
    u = (u + 0x7FFFu + ((u >> 16) & 1u)) >> 16;   // RNE
    return (unsigned short)u;
}

// ---------------------------------------------------------------------------
// prep_w: Wt[mat][n][k] (bf16) <- W[k][n] (fp32).  grid (16,3), block 256.
// Transposed so projection b-frags are contiguous 16B LDS reads.
// ---------------------------------------------------------------------------
__global__ __launch_bounds__(256)
void prep_w_kernel(const float* __restrict__ Wq, const float* __restrict__ Wk,
                   const float* __restrict__ Wv, unsigned short* __restrict__ Wt)
{
    const int mat = blockIdx.y;
    const float* __restrict__ W = (mat == 0) ? Wq : (mat == 1) ? Wk : Wv;
    const int k0 = blockIdx.x * 64;
    __shared__ float T[64][65];
    const int t = threadIdx.x;
    #pragma unroll
    for (int i = 0; i < 16; ++i) {
        const int idx = t + i * 256;
        T[idx >> 6][idx & 63] = W[(size_t)(k0 + (idx >> 6)) * HD + (idx & 63)];
    }
    __syncthreads();
    const int n = t >> 2;
    const int c = t & 3;   // 16-element k chunk
    union { unsigned short h[16]; uint4 v[2]; } buf;
    #pragma unroll
    for (int j = 0; j < 16; ++j) buf.h[j] = f2bf(T[c * 16 + j][n]);
    unsigned short* dst = Wt + ((size_t)mat * HD + n) * DIM + k0 + c * 16;
    *(uint4*)dst       = buf.v[0];
    *(uint4*)(dst + 8) = buf.v[1];
}

// ---------------------------------------------------------------------------
// qkv_mfma: [32 rows] x [192 cols] per block, BK=64, mfma_f32_16x16x32_bf16.
// grid 512, block 128 (2 waves; wave w owns rows w*16..w*16+15, all 192 cols).
// Outputs: Q,K row-major bf16 [16384][64]; V transposed bf16 [B][64][2048].
// ---------------------------------------------------------------------------
__global__ __launch_bounds__(128)
void qkv_mfma_kernel(const float* __restrict__ x,
                     const unsigned short* __restrict__ Wt,
                     const float* __restrict__ bq, const float* __restrict__ bk,
                     const float* __restrict__ bv,
                     unsigned short* __restrict__ Qg,
                     unsigned short* __restrict__ Kg,
                     unsigned short* __restrict__ Vtg)
{
    __shared__ unsigned short Xs[32][72];    // rows padded to 144 B
    __shared__ unsigned short Ws[192][72];

    const int t    = threadIdx.x;
    const int row0 = blockIdx.x * 32;
    const int lane = t & 63;
    const int w    = t >> 6;
    const int col  = lane & 15;
    const int quad = lane >> 4;

    f32x4 acc[12];
    #pragma unroll
    for (int i = 0; i < 12; ++i) acc[i] = (f32x4){0.f, 0.f, 0.f, 0.f};

    for (int k0 = 0; k0 < DIM; k0 += 64) {
        __syncthreads();
        // X tile: 32 rows x 64 k, fp32 -> bf16.  512 float4 units / 128 thr.
        #pragma unroll
        for (int i = 0; i < 4; ++i) {
            const int idx = t + i * 128;
            const int r = idx >> 4, c4 = idx & 15;
            const float4 v = *(const float4*)&x[(size_t)(row0 + r) * DIM + k0 + c4 * 4];
            const unsigned lo = (unsigned)f2bf(v.x) | ((unsigned)f2bf(v.y) << 16);
            const unsigned hi = (unsigned)f2bf(v.z) | ((unsigned)f2bf(v.w) << 16);
            *(uint2*)&Xs[r][c4 * 4] = make_uint2(lo, hi);
        }
        // Wt tile: 192 rows x 64 k bf16.  1536 16B units / 128 thr.
        #pragma unroll
        for (int i = 0; i < 12; ++i) {
            const int u = t + i * 128;
            const int r = u >> 3, ch = u & 7;
            *(uint4*)&Ws[r][ch * 8] = *(const uint4*)&Wt[(size_t)r * DIM + k0 + ch * 8];
        }
        __syncthreads();
        #pragma unroll
        for (int ks = 0; ks < 2; ++ks) {
            const bf16x8 a = *(const bf16x8*)&Xs[w * 16 + col][quad * 8 + ks * 32];
            #pragma unroll
            for (int nt = 0; nt < 12; ++nt) {
                const bf16x8 b = *(const bf16x8*)&Ws[nt * 16 + col][quad * 8 + ks * 32];
                acc[nt] = __builtin_amdgcn_mfma_f32_16x16x32_bf16(a, b, acc[nt], 0, 0, 0);
            }
        }
    }

    // Epilogue.  C layout: col = lane&15, row = quad*4 + r.
    const int b      = row0 / SEQ;
    const int s_base = (row0 % SEQ) + w * 16 + quad * 4;
    const int grow   = row0 + w * 16 + quad * 4;
    #pragma unroll
    for (int nt = 0; nt < 12; ++nt) {
        const int mat = nt >> 2;
        const int nn  = (nt & 3) * 16 + col;
        const float* __restrict__ bias = (mat == 0) ? bq : (mat == 1) ? bk : bv;
        const float bvv = bias[nn];
        if (mat < 2) {
            unsigned short* __restrict__ o = (mat == 0) ? Qg : Kg;
            #pragma unroll
            for (int r = 0; r < 4; ++r)
                o[(size_t)(grow + r) * HD + nn] = f2bf(acc[nt][r] + bvv);
        } else {
            const unsigned lo = (unsigned)f2bf(acc[nt][0] + bvv) | ((unsigned)f2bf(acc[nt][1] + bvv) << 16);
            const unsigned hi = (unsigned)f2bf(acc[nt][2] + bvv) | ((unsigned)f2bf(acc[nt][3] + bvv) << 16);
            *(uint2*)&Vtg[((size_t)b * HD + nn) * SEQ + s_base] = make_uint2(lo, hi);
        }
    }
}

// ---------------------------------------------------------------------------
// attn_mfma: flash attention, MFMA QK^T and PV.  block = 128 thr (2 waves),
// wave = 16 q rows.  K-tiles of 64 keys staged in LDS.  Block x is swizzled
// so q-tile j pairs with 63-j (uniform work per CU pair).
// ---------------------------------------------------------------------------
__global__ __launch_bounds__(128)
void attn_mfma_kernel(const unsigned short* __restrict__ Qg,
                      const unsigned short* __restrict__ Kg,
                      const unsigned short* __restrict__ Vtg,
                      float* __restrict__ out)
{
    __shared__ unsigned short Ks[64][72];      // [key][d]
    __shared__ unsigned short Vs[64][72];      // [d][key]  (from Vtg)
    __shared__ unsigned short Ps[2][16][72];   // per-wave P in A layout [m][key]

    const int t    = threadIdx.x;
    const int w    = t >> 6;
    const int lane = t & 63;
    const int col  = lane & 15;
    const int quad = lane >> 4;

    // swizzle: pair tile j with 63-j so block x and x+256 sum to const work
    const int xb   = blockIdx.x;
    const int half = xb >> 8;
    const int i    = xb & 255;
    const int b    = i >> 5;
    const int j    = i & 31;
    const int tile = half ? (63 - j) : j;
    const int q0w  = tile * 32 + w * 16;          // within batch
    const size_t gq = (size_t)b * SEQ + q0w;      // global row base for wave

    // Q fragments live in registers for the whole kernel (A layout)
    const bf16x8 aq0 = *(const bf16x8*)&Qg[(gq + col) * HD + quad * 8];
    const bf16x8 aq1 = *(const bf16x8*)&Qg[(gq + col) * HD + 32 + quad * 8];

    f32x4 oacc[4];
    #pragma unroll
    for (int n = 0; n < 4; ++n) oacc[n] = (f32x4){0.f, 0.f, 0.f, 0.f};
    float mrow[4], lrow[4];
    #pragma unroll
    for (int r = 0; r < 4; ++r) { mrow[r] = -INFINITY; lrow[r] = 0.f; }

    const int ntiles = (tile >> 1) + 1;
    for (int t0 = 0; t0 < ntiles; ++t0) {
        const int j0 = t0 * 64;
        __syncthreads();
        // stage K tile (64x64) and V^T tile (64x64): 512 16B units each
        #pragma unroll
        for (int ii = 0; ii < 4; ++ii) {
            const int u = t + ii * 128;
            const int r = u >> 3, ch = u & 7;
            *(uint4*)&Ks[r][ch * 8] = *(const uint4*)&Kg[((size_t)b * SEQ + j0 + r) * HD + ch * 8];
            *(uint4*)&Vs[r][ch * 8] = *(const uint4*)&Vtg[((size_t)b * HD + r) * SEQ + j0 + ch * 8];
        }
        __syncthreads();

        // scores: S = Q K^T over 4 sub-tiles of 16 keys
        f32x4 sc[4];
        #pragma unroll
        for (int nt = 0; nt < 4; ++nt) {
            const bf16x8 bk0 = *(const bf16x8*)&Ks[nt * 16 + col][quad * 8];
            const bf16x8 bk1 = *(const bf16x8*)&Ks[nt * 16 + col][32 + quad * 8];
            f32x4 s = __builtin_amdgcn_mfma_f32_16x16x32_bf16(aq0, bk0, (f32x4){0.f,0.f,0.f,0.f}, 0, 0, 0);
            s = __builtin_amdgcn_mfma_f32_16x16x32_bf16(aq1, bk1, s, 0, 0, 0);
            sc[nt] = s;
        }

        // online softmax per row r (rows quad*4+r; 16 cols live in this quad)
        #pragma unroll
        for (int r = 0; r < 4; ++r) {
            const int row = q0w + quad * 4 + r;
            float sv[4];
            float tmax = -INFINITY;
            #pragma unroll
            for (int nt = 0; nt < 4; ++nt) {
                const int key = j0 + nt * 16 + col;
                const float s = (key <= row) ? sc[nt][r] * 0.125f : -INFINITY;
                sv[nt] = s;
                tmax = fmaxf(tmax, s);
            }
            #pragma unroll
            for (int off = 1; off < 16; off <<= 1)
                tmax = fmaxf(tmax, __shfl_xor(tmax, off, 64));
            const float mnew  = fmaxf(mrow[r], tmax);
            const float alpha = __expf(mrow[r] - mnew);   // 0 on first tile
            mrow[r] = mnew;
            float psum = 0.f;
            unsigned short ph[4];
            #pragma unroll
            for (int nt = 0; nt < 4; ++nt) {
                const float p = __expf(sv[nt] - mnew);    // masked -> 0
                psum += p;
                ph[nt] = f2bf(p);
            }
            #pragma unroll
            for (int off = 1; off < 16; off <<= 1)
                psum += __shfl_xor(psum, off, 64);
            lrow[r] = lrow[r] * alpha + psum;
            #pragma unroll
            for (int n = 0; n < 4; ++n) oacc[n][r] *= alpha;
            #pragma unroll
            for (int nt = 0; nt < 4; ++nt)
                Ps[w][quad * 4 + r][nt * 16 + col] = ph[nt];  // same-wave LDS
        }

        // PV: O += P V   (A = P from LDS, B = V^T rows)
        #pragma unroll
        for (int ks = 0; ks < 2; ++ks) {
            const bf16x8 ap = *(const bf16x8*)&Ps[w][col][ks * 32 + quad * 8];
            #pragma unroll
            for (int n = 0; n < 4; ++n) {
                const bf16x8 bv = *(const bf16x8*)&Vs[n * 16 + col][ks * 32 + quad * 8];
                oacc[n] = __builtin_amdgcn_mfma_f32_16x16x32_bf16(ap, bv, oacc[n], 0, 0, 0);
            }
        }
    }

    // epilogue: out fp32 [B*S][64], C layout
    #pragma unroll
    for (int n = 0; n < 4; ++n)
        #pragma unroll
        for (int r = 0; r < 4; ++r)
            out[(gq + quad * 4 + r) * HD + n * 16 + col] = oacc[n][r] / lrow[r];
}

// ---------------------------------------------------------------------------
extern "C" void kernel_launch(void* const* d_in, const int* in_sizes, int n_in,
                              void* d_out, int out_size, void* d_ws, size_t ws_size,
                              hipStream_t stream) {
    const float* x  = (const float*)d_in[0];
    const float* Wq = (const float*)d_in[1];
    const float* bq = (const float*)d_in[2];
    const float* Wk = (const float*)d_in[3];
    const float* bk = (const float*)d_in[4];
    const float* Wv = (const float*)d_in[5];
    const float* bv = (const float*)d_in[6];
    float* out = (float*)d_out;

    unsigned short* Wt  = (unsigned short*)d_ws;          // [3][64][1024] bf16
    unsigned short* Qg  = Wt + (size_t)3 * HD * DIM;      // [16384][64] bf16
    unsigned short* Kg  = Qg + (size_t)NROWS * HD;        // [16384][64] bf16
    unsigned short* Vtg = Kg + (size_t)NROWS * HD;        // [8][64][2048] bf16

    prep_w_kernel<<<dim3(16, 3), 256, 0, stream>>>(Wq, Wk, Wv, Wt);
    qkv_mfma_kernel<<<dim3(NROWS / 32), 128, 0, stream>>>(x, Wt, bq, bk, bv, Qg, Kg, Vtg);
    attn_mfma_kernel<<<dim3(512), 128, 0, stream>>>(Qg, Kg, Vtg, out);
}

// Round 3
// 165.880 us; speedup vs baseline: 3.1472x; 1.4829x over previous
//
#include <hip/hip_runtime.h>
#include <math.h>

#define BATCH 8
#define SEQ   2048
#define DIM   1024
#define HD    64
#define NROWS (BATCH * SEQ)   // 16384
#define CHUNK 512
#define NCHUNK 4              // SEQ / CHUNK
#define QTILE 32              // q rows per attention block
#define NQT   (SEQ / QTILE)   // 64

typedef __attribute__((ext_vector_type(8))) short bf16x8;  // 8 bf16 = 4 VGPRs
typedef __attribute__((ext_vector_type(4))) float f32x4;

__device__ __forceinline__ unsigned short f2bf(float f) {
    unsigned u = __float_as_uint(f);
    u = (u + 0x7FFFu + ((u >> 16) & 1u)) >> 16;   // RNE
    return (unsigned short)u;
}

// async global -> LDS DMA, 16 B per lane.  LDS dest = wave-uniform base + lane*16.
__device__ __forceinline__ void gld_lds16(const void* g, void* l) {
    __builtin_amdgcn_global_load_lds(
        (const __attribute__((address_space(1))) void*)g,
        (__attribute__((address_space(3))) void*)l, 16, 0, 0);
}

// ---------------------------------------------------------------------------
// prep_w: Wt[mat][n][k] (bf16) <- W[k][n] (fp32).  grid (16,3), block 256.
// ---------------------------------------------------------------------------
__global__ __launch_bounds__(256)
void prep_w_kernel(const float* __restrict__ Wq, const float* __restrict__ Wk,
                   const float* __restrict__ Wv, unsigned short* __restrict__ Wt)
{
    const int mat = blockIdx.y;
    const float* __restrict__ W = (mat == 0) ? Wq : (mat == 1) ? Wk : Wv;
    const int k0 = blockIdx.x * 64;
    __shared__ float T[64][65];
    const int t = threadIdx.x;
    #pragma unroll
    for (int i = 0; i < 16; ++i) {
        const int idx = t + i * 256;
        T[idx >> 6][idx & 63] = W[(size_t)(k0 + (idx >> 6)) * HD + (idx & 63)];
    }
    __syncthreads();
    const int n = t >> 2;
    const int c = t & 3;
    union { unsigned short h[16]; uint4 v[2]; } buf;
    #pragma unroll
    for (int j = 0; j < 16; ++j) buf.h[j] = f2bf(T[c * 16 + j][n]);
    unsigned short* dst = Wt + ((size_t)mat * HD + n) * DIM + k0 + c * 16;
    *(uint4*)dst       = buf.v[0];
    *(uint4*)(dst + 8) = buf.v[1];
}

// ---------------------------------------------------------------------------
// qkv_mfma: tile 32 rows x 192 cols, BK=64.  grid 512, block 256 (4 waves;
// wave = 16 rows x 96 cols = 6 acc tiles) -> 2048 waves = 2/SIMD.
// W staged via global_load_lds; X staged via VGPR (fp32->bf16 convert).
// Outputs: Q,K row-major bf16 [16384][64]; V transposed bf16 [B][64][2048].
// ---------------------------------------------------------------------------
__global__ __launch_bounds__(256)
void qkv_mfma_kernel(const float* __restrict__ x,
                     const unsigned short* __restrict__ Wt,
                     const float* __restrict__ bq, const float* __restrict__ bk,
                     const float* __restrict__ bv,
                     unsigned short* __restrict__ Qg,
                     unsigned short* __restrict__ Kg,
                     unsigned short* __restrict__ Vtg)
{
    __shared__ unsigned short Xs[32][64];    // unpadded: DMA-compatible frag layout
    __shared__ unsigned short Ws[192][64];

    const int t    = threadIdx.x;
    const int lane = t & 63;
    const int w    = t >> 6;
    const int col  = lane & 15;
    const int quad = lane >> 4;
    const int rh   = w & 1;       // 16-row half
    const int chh  = w >> 1;      // 96-col half
    const int row0 = blockIdx.x * 32;

    const int xr  = t >> 3,  xc  = t & 7;       // X staging: row, 16B chunk
    const int wrl = lane >> 3, wcl = lane & 7;  // W DMA lane mapping

    f32x4 acc[6];
    #pragma unroll
    for (int i = 0; i < 6; ++i) acc[i] = (f32x4){0.f, 0.f, 0.f, 0.f};

    for (int k0 = 0; k0 < DIM; k0 += 64) {
        __syncthreads();
        // W tile: 192 rows x 64 k via DMA (6 wave-calls x 8 rows)
        #pragma unroll
        for (int ii = 0; ii < 6; ++ii) {
            const int rbase = w * 48 + ii * 8;
            gld_lds16(&Wt[(size_t)(rbase + wrl) * DIM + k0 + wcl * 8], &Ws[rbase][0]);
        }
        // X tile: 32 rows x 64 k, fp32 -> bf16 (1 chunk of 8 per thread)
        {
            const float* xp = &x[(size_t)(row0 + xr) * DIM + k0 + xc * 8];
            const float4 v0 = *(const float4*)xp;
            const float4 v1 = *(const float4*)(xp + 4);
            uint4 o;
            o.x = (unsigned)f2bf(v0.x) | ((unsigned)f2bf(v0.y) << 16);
            o.y = (unsigned)f2bf(v0.z) | ((unsigned)f2bf(v0.w) << 16);
            o.z = (unsigned)f2bf(v1.x) | ((unsigned)f2bf(v1.y) << 16);
            o.w = (unsigned)f2bf(v1.z) | ((unsigned)f2bf(v1.w) << 16);
            *(uint4*)&Xs[xr][xc * 8] = o;
        }
        __syncthreads();
        #pragma unroll
        for (int ks = 0; ks < 2; ++ks) {
            const bf16x8 a = *(const bf16x8*)&Xs[rh * 16 + col][ks * 32 + quad * 8];
            #pragma unroll
            for (int nt = 0; nt < 6; ++nt) {
                const bf16x8 b = *(const bf16x8*)&Ws[chh * 96 + nt * 16 + col][ks * 32 + quad * 8];
                acc[nt] = __builtin_amdgcn_mfma_f32_16x16x32_bf16(a, b, acc[nt], 0, 0, 0);
            }
        }
    }

    // Epilogue.  C layout: col = lane&15, row = quad*4 + r.
    const int b    = row0 / SEQ;
    const int s0   = (row0 % SEQ) + rh * 16 + quad * 4;
    const int grow = row0 + rh * 16 + quad * 4;
    #pragma unroll
    for (int nt = 0; nt < 6; ++nt) {
        const int gcol = chh * 96 + nt * 16 + col;
        const int mat  = gcol >> 6;
        const int nn   = gcol & 63;
        const float bvv = ((mat == 0) ? bq : (mat == 1) ? bk : bv)[nn];
        if (mat < 2) {
            unsigned short* __restrict__ o = (mat == 0) ? Qg : Kg;
            #pragma unroll
            for (int r = 0; r < 4; ++r)
                o[(size_t)(grow + r) * HD + nn] = f2bf(acc[nt][r] + bvv);
        } else {
            const unsigned lo = (unsigned)f2bf(acc[nt][0] + bvv) | ((unsigned)f2bf(acc[nt][1] + bvv) << 16);
            const unsigned hi = (unsigned)f2bf(acc[nt][2] + bvv) | ((unsigned)f2bf(acc[nt][3] + bvv) << 16);
            *(uint2*)&Vtg[((size_t)b * HD + nn) * SEQ + s0] = make_uint2(lo, hi);
        }
    }
}

// ---------------------------------------------------------------------------
// attn_part: split-key flash attention.  block = (b, qtile, chunk of 512 keys),
// 128 thr (2 waves x 16 q rows).  Emits un-normalized partial O' + (m, l).
// grid 2048; blocks with qt < 16*c exit (chunk fully above diagonal).
// ---------------------------------------------------------------------------
__global__ __launch_bounds__(128)
void attn_part_kernel(const unsigned short* __restrict__ Qg,
                      const unsigned short* __restrict__ Kg,
                      const unsigned short* __restrict__ Vtg,
                      float* __restrict__ Opart,   // [2048][32][64]
                      float* __restrict__ ML)      // [2048][64]: 32 m + 32 l
{
    const int xb = blockIdx.x;
    const int c  = xb >> 9;
    const int b  = (xb >> 6) & 7;
    const int qt = xb & 63;
    if (qt < c * 16) return;   // no keys at/below diagonal in this chunk

    __shared__ unsigned short Ks[64][64];     // [key][d]   (DMA: unpadded)
    __shared__ unsigned short Vs[64][64];     // [d][key]   (DMA: unpadded)
    __shared__ unsigned short Ps[2][16][72];  // per-wave P, A layout [m][key]

    const int t    = threadIdx.x;
    const int w    = t >> 6;
    const int lane = t & 63;
    const int col  = lane & 15;
    const int quad = lane >> 4;
    const int q0w  = qt * QTILE + w * 16;
    const size_t gq = (size_t)b * SEQ + q0w;

    const bf16x8 aq0 = *(const bf16x8*)&Qg[(gq + col) * HD + quad * 8];
    const bf16x8 aq1 = *(const bf16x8*)&Qg[(gq + col) * HD + 32 + quad * 8];

    f32x4 oacc[4];
    #pragma unroll
    for (int n = 0; n < 4; ++n) oacc[n] = (f32x4){0.f, 0.f, 0.f, 0.f};
    float mrow[4], lrow[4];
    #pragma unroll
    for (int r = 0; r < 4; ++r) { mrow[r] = -INFINITY; lrow[r] = 0.f; }

    const int kbeg   = c * CHUNK;
    const int kend   = min((c + 1) * CHUNK, (qt + 1) * QTILE);
    const int ntiles = (kend - kbeg + 63) >> 6;

    const int srow = lane >> 3, sc8 = lane & 7;
    const unsigned short* kgb = Kg  + (size_t)b * SEQ * HD;
    const unsigned short* vgb = Vtg + (size_t)b * HD * SEQ;

    for (int it = 0; it < ntiles; ++it) {
        const int j0 = kbeg + it * 64;
        __syncthreads();
        // stage K (8 KB) + V^T (8 KB) via DMA: 4 wave-calls x 8 rows each
        #pragma unroll
        for (int ii = 0; ii < 4; ++ii) {
            const int rb = w * 32 + ii * 8;
            gld_lds16(&kgb[(size_t)(j0 + rb + srow) * HD + sc8 * 8], &Ks[rb][0]);
            gld_lds16(&vgb[(size_t)(rb + srow) * SEQ + j0 + sc8 * 8], &Vs[rb][0]);
        }
        __syncthreads();

        if (j0 <= q0w + 15) {   // wave-uniform: skip fully-masked tiles
            // scores
            f32x4 scv[4];
            #pragma unroll
            for (int nt = 0; nt < 4; ++nt) {
                const bf16x8 bk0 = *(const bf16x8*)&Ks[nt * 16 + col][quad * 8];
                const bf16x8 bk1 = *(const bf16x8*)&Ks[nt * 16 + col][32 + quad * 8];
                f32x4 s = __builtin_amdgcn_mfma_f32_16x16x32_bf16(aq0, bk0, (f32x4){0.f,0.f,0.f,0.f}, 0, 0, 0);
                s = __builtin_amdgcn_mfma_f32_16x16x32_bf16(aq1, bk1, s, 0, 0, 0);
                scv[nt] = s;
            }
            const bool needmask = (j0 + 63 > q0w);
            #pragma unroll
            for (int r = 0; r < 4; ++r) {
                const int row = q0w + quad * 4 + r;
                float sv[4];
                float tmax = -INFINITY;
                if (needmask) {
                    #pragma unroll
                    for (int nt = 0; nt < 4; ++nt) {
                        const int key = j0 + nt * 16 + col;
                        sv[nt] = (key <= row) ? scv[nt][r] * 0.125f : -INFINITY;
                        tmax = fmaxf(tmax, sv[nt]);
                    }
                } else {
                    #pragma unroll
                    for (int nt = 0; nt < 4; ++nt) {
                        sv[nt] = scv[nt][r] * 0.125f;
                        tmax = fmaxf(tmax, sv[nt]);
                    }
                }
                #pragma unroll
                for (int off = 1; off < 16; off <<= 1)
                    tmax = fmaxf(tmax, __shfl_xor(tmax, off, 64));
                const float mnew  = fmaxf(mrow[r], tmax);
                const float alpha = __expf(mrow[r] - mnew);
                mrow[r] = mnew;
                float psum = 0.f;
                #pragma unroll
                for (int nt = 0; nt < 4; ++nt) {
                    const float p = __expf(sv[nt] - mnew);
                    psum += p;
                    Ps[w][quad * 4 + r][nt * 16 + col] = f2bf(p);  // same-wave LDS
                }
                #pragma unroll
                for (int off = 1; off < 16; off <<= 1)
                    psum += __shfl_xor(psum, off, 64);
                lrow[r] = lrow[r] * alpha + psum;
                #pragma unroll
                for (int n = 0; n < 4; ++n) oacc[n][r] *= alpha;
            }
            // PV
            #pragma unroll
            for (int ks = 0; ks < 2; ++ks) {
                const bf16x8 ap = *(const bf16x8*)&Ps[w][col][ks * 32 + quad * 8];
                #pragma unroll
                for (int n = 0; n < 4; ++n) {
                    const bf16x8 bv2 = *(const bf16x8*)&Vs[n * 16 + col][ks * 32 + quad * 8];
                    oacc[n] = __builtin_amdgcn_mfma_f32_16x16x32_bf16(ap, bv2, oacc[n], 0, 0, 0);
                }
            }
        }
    }

    // epilogue: un-normalized partials
    const int blk = (b * NQT + qt) * NCHUNK + c;
    float* Ob = Opart + (size_t)blk * (QTILE * HD);
    #pragma unroll
    for (int n = 0; n < 4; ++n)
        #pragma unroll
        for (int r = 0; r < 4; ++r)
            Ob[(w * 16 + quad * 4 + r) * HD + n * 16 + col] = oacc[n][r];
    if (col == 0) {
        float* mlb = ML + (size_t)blk * 64;
        #pragma unroll
        for (int r = 0; r < 4; ++r) {
            mlb[w * 16 + quad * 4 + r]      = mrow[r];
            mlb[32 + w * 16 + quad * 4 + r] = lrow[r];
        }
    }
}

// ---------------------------------------------------------------------------
// combine: merge up to 4 partials per row.  grid 4096 x 256 (1 thread per
// (row, dim)).
// ---------------------------------------------------------------------------
__global__ __launch_bounds__(256)
void combine_kernel(const float* __restrict__ Opart,
                    const float* __restrict__ ML,
                    float* __restrict__ out)
{
    const int gid = blockIdx.x * 256 + threadIdx.x;
    const int i   = gid >> 6;      // global row
    const int d   = gid & 63;
    const int b   = i >> 11;
    const int s   = i & 2047;
    const int qt  = s >> 5;
    const int r32 = s & 31;
    const int nc  = (s >> 9) + 1;
    const int blk0 = (b * NQT + qt) * NCHUNK;

    float m[NCHUNK], l[NCHUNK];
    float M = -INFINITY;
    for (int cc = 0; cc < nc; ++cc) {
        m[cc] = ML[(size_t)(blk0 + cc) * 64 + r32];
        l[cc] = ML[(size_t)(blk0 + cc) * 64 + 32 + r32];
        M = fmaxf(M, m[cc]);
    }
    float L = 0.f, acc = 0.f;
    for (int cc = 0; cc < nc; ++cc) {
        const float e = __expf(m[cc] - M);
        L   += l[cc] * e;
        acc += e * Opart[(size_t)(blk0 + cc) * (QTILE * HD) + r32 * HD + d];
    }
    out[(size_t)i * HD + d] = acc / L;
}

// ---------------------------------------------------------------------------
extern "C" void kernel_launch(void* const* d_in, const int* in_sizes, int n_in,
                              void* d_out, int out_size, void* d_ws, size_t ws_size,
                              hipStream_t stream) {
    const float* x  = (const float*)d_in[0];
    const float* Wq = (const float*)d_in[1];
    const float* bq = (const float*)d_in[2];
    const float* Wk = (const float*)d_in[3];
    const float* bk = (const float*)d_in[4];
    const float* Wv = (const float*)d_in[5];
    const float* bv = (const float*)d_in[6];
    float* out = (float*)d_out;

    unsigned short* Wt  = (unsigned short*)d_ws;          // [3][64][1024] bf16
    unsigned short* Qg  = Wt + (size_t)3 * HD * DIM;      // [16384][64] bf16
    unsigned short* Kg  = Qg + (size_t)NROWS * HD;        // [16384][64] bf16
    unsigned short* Vtg = Kg + (size_t)NROWS * HD;        // [8][64][2048] bf16
    float* Opart = (float*)(Vtg + (size_t)BATCH * HD * SEQ);   // [2048][32][64] f32
    float* ML    = Opart + (size_t)BATCH * NQT * NCHUNK * QTILE * HD;  // [2048][64]

    prep_w_kernel<<<dim3(16, 3), 256, 0, stream>>>(Wq, Wk, Wv, Wt);
    qkv_mfma_kernel<<<dim3(NROWS / 32), 256, 0, stream>>>(x, Wt, bq, bk, bv, Qg, Kg, Vtg);
    attn_part_kernel<<<dim3(NCHUNK * BATCH * NQT), 128, 0, stream>>>(Qg, Kg, Vtg, Opart, ML);
    combine_kernel<<<dim3(NROWS * HD / 256), 256, 0, stream>>>(Opart, ML, out);
}

// Round 4
// 160.074 us; speedup vs baseline: 3.2613x; 1.0363x over previous
//
#include <hip/hip_runtime.h>
#include <math.h>

#define BATCH 8
#define SEQ   2048
#define DIM   1024
#define HD    64
#define NROWS (BATCH * SEQ)   // 16384
#define CHUNK 256
#define NCHUNK 8              // SEQ / CHUNK
#define QTILE 32              // q rows per attention block
#define NQT   (SEQ / QTILE)   // 64

typedef __attribute__((ext_vector_type(8))) short bf16x8;  // 8 bf16 = 4 VGPRs
typedef __attribute__((ext_vector_type(4))) float f32x4;

__device__ __forceinline__ unsigned short f2bf(float f) {
    unsigned u = __float_as_uint(f);
    u = (u + 0x7FFFu + ((u >> 16) & 1u)) >> 16;   // RNE
    return (unsigned short)u;
}

// async global -> LDS DMA, 16 B per lane.  LDS dest = wave-uniform base + lane*16.
__device__ __forceinline__ void gld_lds16(const void* g, void* l) {
    __builtin_amdgcn_global_load_lds(
        (const __attribute__((address_space(1))) void*)g,
        (__attribute__((address_space(3))) void*)l, 16, 0, 0);
}

// LDS layout for 64-col bf16 tiles: row r, 8-short chunk c stored at chunk
// c ^ (r & 7).  DMA side: lane (r8 = lane>>3, ch = lane&7) must LOAD global
// chunk ch ^ r8.  Frag-read side: chunk (ks*4+quad) ^ (col&7).  This spreads
// the 16 cols of a quad over all 32 banks (2-way max = free).

// ---------------------------------------------------------------------------
// prep_w: Wt[mat][n][k] (bf16) <- W[k][n] (fp32).  grid (16,3), block 256.
// ---------------------------------------------------------------------------
__global__ __launch_bounds__(256)
void prep_w_kernel(const float* __restrict__ Wq, const float* __restrict__ Wk,
                   const float* __restrict__ Wv, unsigned short* __restrict__ Wt)
{
    const int mat = blockIdx.y;
    const float* __restrict__ W = (mat == 0) ? Wq : (mat == 1) ? Wk : Wv;
    const int k0 = blockIdx.x * 64;
    __shared__ float T[64][65];
    const int t = threadIdx.x;
    #pragma unroll
    for (int i = 0; i < 16; ++i) {
        const int idx = t + i * 256;
        T[idx >> 6][idx & 63] = W[(size_t)(k0 + (idx >> 6)) * HD + (idx & 63)];
    }
    __syncthreads();
    const int n = t >> 2;
    const int c = t & 3;
    union { unsigned short h[16]; uint4 v[2]; } buf;
    #pragma unroll
    for (int j = 0; j < 16; ++j) buf.h[j] = f2bf(T[c * 16 + j][n]);
    unsigned short* dst = Wt + ((size_t)mat * HD + n) * DIM + k0 + c * 16;
    *(uint4*)dst       = buf.v[0];
    *(uint4*)(dst + 8) = buf.v[1];
}

// ---------------------------------------------------------------------------
// qkv_mfma: tile 32 rows x 192 cols, BK=64, block 384 thr = 6 waves.
// wave w: rows (w&1)*16..+15, cols (w>>2? no: mat = w>>1)*64..+63 -> 4 acc.
// grid 512 -> 3072 waves (3/SIMD).  Ws via swizzled DMA, Xs via swizzled
// manual store (fp32->bf16).  Outputs: Q,K row-major bf16; V^T bf16 [B][64][S].
// ---------------------------------------------------------------------------
__global__ __launch_bounds__(384)
void qkv_mfma_kernel(const float* __restrict__ x,
                     const unsigned short* __restrict__ Wt,
                     const float* __restrict__ bq, const float* __restrict__ bk,
                     const float* __restrict__ bv,
                     unsigned short* __restrict__ Qg,
                     unsigned short* __restrict__ Kg,
                     unsigned short* __restrict__ Vtg)
{
    __shared__ unsigned short Xs[32][64];    // swizzled chunks
    __shared__ unsigned short Ws[192][64];   // swizzled chunks

    const int t    = threadIdx.x;
    const int lane = t & 63;
    const int w    = t >> 6;         // 0..5
    const int col  = lane & 15;
    const int quad = lane >> 4;
    const int rh   = w & 1;          // 16-row half
    const int mat  = w >> 1;         // 0=Q, 1=K, 2=V
    const int row0 = blockIdx.x * 32;

    const int r8 = lane >> 3, ch = lane & 7;    // DMA lane mapping
    const int xr = t >> 3,  xc = t & 7;         // X staging (t < 256)

    f32x4 acc[4];
    #pragma unroll
    for (int i = 0; i < 4; ++i) acc[i] = (f32x4){0.f, 0.f, 0.f, 0.f};

    const int swzr = (ch ^ r8) * 8;             // swizzled source chunk offset

    for (int k0 = 0; k0 < DIM; k0 += 64) {
        __syncthreads();
        // W tile: 192 rows x 64 k via swizzled DMA (6 waves x 4 calls x 8 rows)
        #pragma unroll
        for (int ii = 0; ii < 4; ++ii) {
            const int rbase = w * 32 + ii * 8;
            gld_lds16(&Wt[(size_t)(rbase + r8) * DIM + k0 + swzr], &Ws[rbase][0]);
        }
        // X tile: 32 rows x 64 k, fp32 -> bf16, stored swizzled
        if (t < 256) {
            const float* xp = &x[(size_t)(row0 + xr) * DIM + k0 + xc * 8];
            const float4 v0 = *(const float4*)xp;
            const float4 v1 = *(const float4*)(xp + 4);
            uint4 o;
            o.x = (unsigned)f2bf(v0.x) | ((unsigned)f2bf(v0.y) << 16);
            o.y = (unsigned)f2bf(v0.z) | ((unsigned)f2bf(v0.w) << 16);
            o.z = (unsigned)f2bf(v1.x) | ((unsigned)f2bf(v1.y) << 16);
            o.w = (unsigned)f2bf(v1.z) | ((unsigned)f2bf(v1.w) << 16);
            *(uint4*)&Xs[xr][(xc ^ (xr & 7)) * 8] = o;
        }
        __syncthreads();
        #pragma unroll
        for (int ks = 0; ks < 2; ++ks) {
            const int fswz = ((ks * 4 + quad) ^ (col & 7)) * 8;
            const bf16x8 a = *(const bf16x8*)&Xs[rh * 16 + col][fswz];
            #pragma unroll
            for (int nt = 0; nt < 4; ++nt) {
                const bf16x8 b = *(const bf16x8*)&Ws[mat * 64 + nt * 16 + col][fswz];
                acc[nt] = __builtin_amdgcn_mfma_f32_16x16x32_bf16(a, b, acc[nt], 0, 0, 0);
            }
        }
    }

    // Epilogue.  C layout: col = lane&15, row = quad*4 + r.
    const int b    = row0 / SEQ;
    const int s0   = (row0 % SEQ) + rh * 16 + quad * 4;
    const int grow = row0 + rh * 16 + quad * 4;
    const float* __restrict__ bias = (mat == 0) ? bq : (mat == 1) ? bk : bv;
    #pragma unroll
    for (int nt = 0; nt < 4; ++nt) {
        const int nn = nt * 16 + col;
        const float bvv = bias[nn];
        if (mat < 2) {
            unsigned short* __restrict__ o = (mat == 0) ? Qg : Kg;
            #pragma unroll
            for (int r = 0; r < 4; ++r)
                o[(size_t)(grow + r) * HD + nn] = f2bf(acc[nt][r] + bvv);
        } else {
            const unsigned lo = (unsigned)f2bf(acc[nt][0] + bvv) | ((unsigned)f2bf(acc[nt][1] + bvv) << 16);
            const unsigned hi = (unsigned)f2bf(acc[nt][2] + bvv) | ((unsigned)f2bf(acc[nt][3] + bvv) << 16);
            *(uint2*)&Vtg[((size_t)b * HD + nn) * SEQ + s0] = make_uint2(lo, hi);
        }
    }
}

// ---------------------------------------------------------------------------
// attn_part: split-key flash attention, CHUNK=256 keys per block.
// block = (b, qtile, chunk), 128 thr (2 waves x 16 q rows), <=4 K-iters.
// grid 4096; 2304 valid blocks (4.5 waves/SIMD).  K/V staged via swizzled DMA.
// ---------------------------------------------------------------------------
__global__ __launch_bounds__(128)
void attn_part_kernel(const unsigned short* __restrict__ Qg,
                      const unsigned short* __restrict__ Kg,
                      const unsigned short* __restrict__ Vtg,
                      float* __restrict__ Opart,   // [4096][32][64]
                      float* __restrict__ ML)      // [4096][64]: 32 m + 32 l
{
    const int xb = blockIdx.x;
    const int c  = xb >> 9;
    const int b  = (xb >> 6) & 7;
    const int qt = xb & 63;
    if (qt < c * 8) return;   // chunk fully above diagonal

    __shared__ unsigned short Ks[64][64];     // [key][d], swizzled chunks
    __shared__ unsigned short Vs[64][64];     // [d][key], swizzled chunks
    __shared__ unsigned short Ps[2][16][72];  // per-wave P, A layout [m][key]

    const int t    = threadIdx.x;
    const int w    = t >> 6;
    const int lane = t & 63;
    const int col  = lane & 15;
    const int quad = lane >> 4;
    const int q0w  = qt * QTILE + w * 16;
    const size_t gq = (size_t)b * SEQ + q0w;

    const bf16x8 aq0 = *(const bf16x8*)&Qg[(gq + col) * HD + quad * 8];
    const bf16x8 aq1 = *(const bf16x8*)&Qg[(gq + col) * HD + 32 + quad * 8];

    f32x4 oacc[4];
    #pragma unroll
    for (int n = 0; n < 4; ++n) oacc[n] = (f32x4){0.f, 0.f, 0.f, 0.f};
    float mrow[4], lrow[4];
    #pragma unroll
    for (int r = 0; r < 4; ++r) { mrow[r] = -INFINITY; lrow[r] = 0.f; }

    const int kbeg   = c * CHUNK;
    const int kend   = min((c + 1) * CHUNK, (qt + 1) * QTILE);
    const int ntiles = (kend - kbeg + 63) >> 6;

    const int r8 = lane >> 3, ch = lane & 7;
    const int swzr = (ch ^ r8) * 8;
    const unsigned short* kgb = Kg  + (size_t)b * SEQ * HD;
    const unsigned short* vgb = Vtg + (size_t)b * HD * SEQ;

    for (int it = 0; it < ntiles; ++it) {
        const int j0 = kbeg + it * 64;
        __syncthreads();
        // stage K (8 KB) + V^T (8 KB) via swizzled DMA: 4 wave-calls x 8 rows
        #pragma unroll
        for (int ii = 0; ii < 4; ++ii) {
            const int rb = w * 32 + ii * 8;
            gld_lds16(&kgb[(size_t)(j0 + rb + r8) * HD + swzr], &Ks[rb][0]);
            gld_lds16(&vgb[(size_t)(rb + r8) * SEQ + j0 + swzr], &Vs[rb][0]);
        }
        __syncthreads();

        if (j0 <= q0w + 15) {   // wave-uniform: skip fully-masked tiles
            // scores
            f32x4 scv[4];
            #pragma unroll
            for (int nt = 0; nt < 4; ++nt) {
                const int sw0 = (quad ^ (col & 7)) * 8;
                const int sw1 = ((4 + quad) ^ (col & 7)) * 8;
                const bf16x8 bk0 = *(const bf16x8*)&Ks[nt * 16 + col][sw0];
                const bf16x8 bk1 = *(const bf16x8*)&Ks[nt * 16 + col][sw1];
                f32x4 s = __builtin_amdgcn_mfma_f32_16x16x32_bf16(aq0, bk0, (f32x4){0.f,0.f,0.f,0.f}, 0, 0, 0);
                s = __builtin_amdgcn_mfma_f32_16x16x32_bf16(aq1, bk1, s, 0, 0, 0);
                scv[nt] = s;
            }
            const bool needmask = (j0 + 63 > q0w);
            #pragma unroll
            for (int r = 0; r < 4; ++r) {
                const int row = q0w + quad * 4 + r;
                float sv[4];
                float tmax = -INFINITY;
                if (needmask) {
                    #pragma unroll
                    for (int nt = 0; nt < 4; ++nt) {
                        const int key = j0 + nt * 16 + col;
                        sv[nt] = (key <= row) ? scv[nt][r] * 0.125f : -INFINITY;
                        tmax = fmaxf(tmax, sv[nt]);
                    }
                } else {
                    #pragma unroll
                    for (int nt = 0; nt < 4; ++nt) {
                        sv[nt] = scv[nt][r] * 0.125f;
                        tmax = fmaxf(tmax, sv[nt]);
                    }
                }
                #pragma unroll
                for (int off = 1; off < 16; off <<= 1)
                    tmax = fmaxf(tmax, __shfl_xor(tmax, off, 64));
                const float mnew  = fmaxf(mrow[r], tmax);
                const float alpha = __expf(mrow[r] - mnew);
                mrow[r] = mnew;
                float psum = 0.f;
                #pragma unroll
                for (int nt = 0; nt < 4; ++nt) {
                    const float p = __expf(sv[nt] - mnew);
                    psum += p;
                    Ps[w][quad * 4 + r][nt * 16 + col] = f2bf(p);  // same-wave LDS
                }
                #pragma unroll
                for (int off = 1; off < 16; off <<= 1)
                    psum += __shfl_xor(psum, off, 64);
                lrow[r] = lrow[r] * alpha + psum;
                #pragma unroll
                for (int n = 0; n < 4; ++n) oacc[n][r] *= alpha;
            }
            // PV
            #pragma unroll
            for (int ks = 0; ks < 2; ++ks) {
                const bf16x8 ap = *(const bf16x8*)&Ps[w][col][ks * 32 + quad * 8];
                const int fswz = ((ks * 4 + quad) ^ (col & 7)) * 8;
                #pragma unroll
                for (int n = 0; n < 4; ++n) {
                    const bf16x8 bv2 = *(const bf16x8*)&Vs[n * 16 + col][fswz];
                    oacc[n] = __builtin_amdgcn_mfma_f32_16x16x32_bf16(ap, bv2, oacc[n], 0, 0, 0);
                }
            }
        }
    }

    // epilogue: un-normalized partials
    const int blk = (b * NQT + qt) * NCHUNK + c;
    float* Ob = Opart + (size_t)blk * (QTILE * HD);
    #pragma unroll
    for (int n = 0; n < 4; ++n)
        #pragma unroll
        for (int r = 0; r < 4; ++r)
            Ob[(w * 16 + quad * 4 + r) * HD + n * 16 + col] = oacc[n][r];
    if (col == 0) {
        float* mlb = ML + (size_t)blk * 64;
        #pragma unroll
        for (int r = 0; r < 4; ++r) {
            mlb[w * 16 + quad * 4 + r]      = mrow[r];
            mlb[32 + w * 16 + quad * 4 + r] = lrow[r];
        }
    }
}

// ---------------------------------------------------------------------------
// combine: merge up to NCHUNK partials per row.  1 thread per (row, dim).
// ---------------------------------------------------------------------------
__global__ __launch_bounds__(256)
void combine_kernel(const float* __restrict__ Opart,
                    const float* __restrict__ ML,
                    float* __restrict__ out)
{
    const int gid = blockIdx.x * 256 + threadIdx.x;
    const int i   = gid >> 6;      // global row
    const int d   = gid & 63;
    const int b   = i >> 11;
    const int s   = i & 2047;
    const int qt  = s >> 5;
    const int r32 = s & 31;
    const int nc  = (s >> 8) + 1;  // chunks touching this row
    const int blk0 = (b * NQT + qt) * NCHUNK;

    float M = -INFINITY;
    for (int cc = 0; cc < nc; ++cc)
        M = fmaxf(M, ML[(size_t)(blk0 + cc) * 64 + r32]);
    float L = 0.f, acc = 0.f;
    for (int cc = 0; cc < nc; ++cc) {
        const float m = ML[(size_t)(blk0 + cc) * 64 + r32];
        const float l = ML[(size_t)(blk0 + cc) * 64 + 32 + r32];
        const float e = __expf(m - M);
        L   += l * e;
        acc += e * Opart[(size_t)(blk0 + cc) * (QTILE * HD) + r32 * HD + d];
    }
    out[(size_t)i * HD + d] = acc / L;
}

// ---------------------------------------------------------------------------
extern "C" void kernel_launch(void* const* d_in, const int* in_sizes, int n_in,
                              void* d_out, int out_size, void* d_ws, size_t ws_size,
                              hipStream_t stream) {
    const float* x  = (const float*)d_in[0];
    const float* Wq = (const float*)d_in[1];
    const float* bq = (const float*)d_in[2];
    const float* Wk = (const float*)d_in[3];
    const float* bk = (const float*)d_in[4];
    const float* Wv = (const float*)d_in[5];
    const float* bv = (const float*)d_in[6];
    float* out = (float*)d_out;

    unsigned short* Wt  = (unsigned short*)d_ws;          // [3][64][1024] bf16
    unsigned short* Qg  = Wt + (size_t)3 * HD * DIM;      // [16384][64] bf16
    unsigned short* Kg  = Qg + (size_t)NROWS * HD;        // [16384][64] bf16
    unsigned short* Vtg = Kg + (size_t)NROWS * HD;        // [8][64][2048] bf16
    float* Opart = (float*)(Vtg + (size_t)BATCH * HD * SEQ);            // [4096][32][64] f32
    float* ML    = Opart + (size_t)BATCH * NQT * NCHUNK * QTILE * HD;   // [4096][64]

    prep_w_kernel<<<dim3(16, 3), 256, 0, stream>>>(Wq, Wk, Wv, Wt);
    qkv_mfma_kernel<<<dim3(NROWS / 32), 384, 0, stream>>>(x, Wt, bq, bk, bv, Qg, Kg, Vtg);
    attn_part_kernel<<<dim3(NCHUNK * BATCH * NQT), 128, 0, stream>>>(Qg, Kg, Vtg, Opart, ML);
    combine_kernel<<<dim3(NROWS * HD / 256), 256, 0, stream>>>(Opart, ML, out);
}